// Round 2
// baseline (124.522 us; speedup 1.0000x reference)
//
#include <hip/hip_runtime.h>

// Problem constants: B=2, L=2048, H=8, D=64, window=32, stride=64
#define Bc 2
#define Lc 2048
#define Hc 8
#define Dc 64
#define TL 16                 // rows per block
#define NT (Lc / TL)          // 128 tiles
#define RHD (Hc * Dc)         // 512 floats between consecutive s rows
#define SP1 65                // stride+1
#define SCALE 0.125f          // 1/sqrt(64)

// DPP-based add of a permuted copy: pure VALU, no DS traffic.
template <int CTRL>
__device__ __forceinline__ float dpp_add(float x) {
    int p = __builtin_amdgcn_update_dpp(0, __float_as_int(x), CTRL, 0xF, 0xF, true);
    return x + __int_as_float(p);
}
// 16-lane-row sum (verified R3/R4): xor1, xor2, half-mirror, mirror.
__device__ __forceinline__ float row16_sum(float x) {
    x = dpp_add<0xB1>(x);
    x = dpp_add<0x4E>(x);
    x = dpp_add<0x141>(x);
    x = dpp_add<0x140>(x);
    return x;
}

// ---------------------------------------------------------------------------
// Kernel 1: per-(b,h) tile sums of V -> partials[bh][t][d]
// ---------------------------------------------------------------------------
__global__ __launch_bounds__(256)
void dozer_chunk_sum(const float* __restrict__ V, float* __restrict__ partials) {
    const int bh = blockIdx.x;
    const int t  = blockIdx.y;
    const int b  = bh >> 3;
    const int h  = bh & 7;
    const int g  = threadIdx.x >> 6;
    const int d  = threadIdx.x & 63;
    const float* Vbh = V + (size_t)b * Lc * RHD + h * Dc;
    const int l0 = t * TL;
    float s = 0.f;
    for (int r = g; r < TL; r += 4)
        s += Vbh[(size_t)(l0 + r) * RHD + d];
    __shared__ float red[4][64];
    red[g][d] = s;
    __syncthreads();
    if (g == 0)
        partials[((size_t)bh * NT + t) * 64 + d] =
            red[0][d] + red[1][d] + red[2][d] + red[3][d];
}

// ---------------------------------------------------------------------------
// Kernel 2: far corrections via residue chains.
// Rows with l ≡ c (mod 65) form a chain; far offsets (65f) connect ONLY rows
// within the same chain. Block = (bh, c): stage the <=32 chain rows of K and
// V into LDS ONCE (each K/V row is far-read exactly once from global across
// the whole grid), then compute the triangular intra-chain corrections.
// Slot s = wave + 4p owns rows i1 = s and i2 = n-1-s (balanced: i1+i2 = n-1).
// The j-loop is lockstep across slots -> Kc[j]/Vc[j] reads are LDS
// broadcasts (conflict-free, no padding needed).
// Writes facc[bh][l][64] (float4/lane) and fden[bh][l].
// ---------------------------------------------------------------------------
__global__ __launch_bounds__(256)
void dozer_far(const float* __restrict__ Q, const float* __restrict__ K,
               const float* __restrict__ V, float* __restrict__ facc,
               float* __restrict__ fden) {
    const int bh   = blockIdx.x;
    const int c    = blockIdx.y;                 // chain residue 0..64
    const int b    = bh >> 3;
    const int h    = bh & 7;
    const int tid  = threadIdx.x;
    const int wave = tid >> 6;
    const int lane = tid & 63;
    const int p    = lane >> 4;
    const int dd   = lane & 15;
    const int n    = (Lc - 1 - c) / SP1 + 1;     // chain length: 31 or 32

    const float* Qbh = Q + (size_t)b * Lc * RHD + h * Dc;
    const float* Kbh = K + (size_t)b * Lc * RHD + h * Dc;
    const float* Vbh = V + (size_t)b * Lc * RHD + h * Dc;

    __shared__ float Kc[32][64];
    __shared__ float Vc[32][64];

    {   // stage chain rows: 16 rows per round, float4 per lane
        const int ri = tid >> 4;
        const int c4 = (tid & 15) * 4;
        #pragma unroll
        for (int rnd = 0; rnd < 2; ++rnd) {
            const int k = ri + 16 * rnd;
            if (k < n) {
                const size_t row = (size_t)(c + SP1 * k) * RHD;
                *(float4*)&Kc[k][c4] = *(const float4*)(Kbh + row + c4);
                *(float4*)&Vc[k][c4] = *(const float4*)(Vbh + row + c4);
            }
        }
        __syncthreads();
    }

    const int s  = wave + 4 * p;                 // slot 0..15
    const int i1 = s;                            // i1 <= 15
    const int i2 = n - 1 - s;                    // i2 >= 15 >= i1
    const int l1 = c + SP1 * i1;
    const int l2 = c + SP1 * i2;

    float4 q1 = *(const float4*)&Qbh[(size_t)l1 * RHD + dd * 4];
    float4 q2 = *(const float4*)&Qbh[(size_t)l2 * RHD + dd * 4];
    q1.x *= SCALE; q1.y *= SCALE; q1.z *= SCALE; q1.w *= SCALE;
    q2.x *= SCALE; q2.y *= SCALE; q2.z *= SCALE; q2.w *= SCALE;

    float4 a1 = make_float4(0.f, 0.f, 0.f, 0.f);
    float4 a2 = make_float4(0.f, 0.f, 0.f, 0.f);
    float  d1 = 0.f, d2 = 0.f;

    for (int j = 0; j < i2; ++j) {
        const float4 k4 = *(const float4*)&Kc[j][dd * 4];
        const float4 v4 = *(const float4*)&Vc[j][dd * 4];
        // row i2: always active (j < i2 by loop bound)
        float t2 = q2.x * k4.x + q2.y * k4.y + q2.z * k4.z + q2.w * k4.w;
        t2 = row16_sum(t2);
        const float w2 = __expf(t2) - 1.f;
        a2.x += w2 * v4.x; a2.y += w2 * v4.y;
        a2.z += w2 * v4.z; a2.w += w2 * v4.w;
        d2 += w2;
        // row i1: active only while j < i1 (predicated)
        float t1 = q1.x * k4.x + q1.y * k4.y + q1.z * k4.z + q1.w * k4.w;
        t1 = row16_sum(t1);
        float w1 = __expf(t1) - 1.f;
        w1 = (j < i1) ? w1 : 0.f;
        a1.x += w1 * v4.x; a1.y += w1 * v4.y;
        a1.z += w1 * v4.z; a1.w += w1 * v4.w;
        d1 += w1;
    }

    {   // each chain row written exactly once across slots
        float* f2 = facc + ((size_t)bh * Lc + l2) * 64 + dd * 4;
        *(float4*)f2 = a2;
        if (dd == 0) fden[(size_t)bh * Lc + l2] = d2;
        if (i1 != i2) {   // equality only when n==31, s==15
            float* f1 = facc + ((size_t)bh * Lc + l1) * 64 + dd * 4;
            *(float4*)f1 = a1;
            if (dd == 0) fden[(size_t)bh * Lc + l1] = d1;
        }
    }
}

// ---------------------------------------------------------------------------
// Kernel 3: main kernel without the far loop. Prefix (vectorized float4
// partials read) + band from padded LDS (+68 stride: rows start 17 banks
// apart -> conflict-free ds_read_b128) + far correction from facc/fden.
// LDS: 2*8704 + 4096 = 21504 B -> 7 blocks/CU.
// ---------------------------------------------------------------------------
__global__ __launch_bounds__(256)
void dozer_main_lite(const float* __restrict__ Q, const float* __restrict__ K,
                     const float* __restrict__ V, const float* __restrict__ partials,
                     const float* __restrict__ facc, const float* __restrict__ fden,
                     float* __restrict__ out) {
    const int bh   = blockIdx.x;
    const int t    = (NT - 1) - blockIdx.y;   // heavy tiles first
    const int b    = bh >> 3;
    const int h    = bh & 7;
    const int tid  = threadIdx.x;
    const int wave = tid >> 6;
    const int lane = tid & 63;
    const int l0   = t * TL;
    const int p    = lane >> 4;
    const int dd   = lane & 15;

    const float* Qbh = Q + (size_t)b * Lc * RHD + h * Dc;
    const float* Kbh = K + (size_t)b * Lc * RHD + h * Dc;
    const float* Vbh = V + (size_t)b * Lc * RHD + h * Dc;

    __shared__ float Kband[32][68];
    __shared__ float Vband[32][68];
    __shared__ float Ptile[TL][64];
    // redf aliases Kband (20*68*4 = 5440 B < 8704 B): prefix scratch, fully
    // consumed before staging overwrites it.
    float* redf = &Kband[0][0];

    // ---- prefix phase ----
    {
        // vectorized partials read: slot (wave,p) covers c = 16*it + 4*wave + p
        float4 pa = make_float4(0.f, 0.f, 0.f, 0.f);
        const float* pb = partials + (size_t)bh * NT * 64;
        const int itn = (t + 15) >> 4;
        for (int it = 0; it < itn; ++it) {
            const int cc = 16 * it + 4 * wave + p;     // <= 127 always: in-bounds
            const float4 f4 = *(const float4*)(pb + (size_t)cc * 64 + dd * 4);
            if (cc < t) { pa.x += f4.x; pa.y += f4.y; pa.z += f4.z; pa.w += f4.w; }
        }
        *(float4*)&redf[(4 * wave + p) * 68 + dd * 4] = pa;

        // V carry rows (scalar-d layout, as before)
        const int d = lane;
        const float* vr = Vbh + (size_t)(l0 + 4 * wave) * RHD + d;
        const float x0 = vr[0];
        const float x1 = vr[RHD];
        const float x2 = vr[2 * RHD];
        const float x3 = vr[3 * RHD];
        const float s0 = x0, s1 = s0 + x1, s2 = s1 + x2, s3 = s2 + x3;
        redf[(16 + wave) * 68 + d] = s3;
        __syncthreads();
        float base = 0.f;
        #pragma unroll
        for (int r2 = 0; r2 < 16; ++r2) base += redf[r2 * 68 + d];
        if (wave > 0) base += redf[(16 + 0) * 68 + d];
        if (wave > 1) base += redf[(16 + 1) * 68 + d];
        if (wave > 2) base += redf[(16 + 2) * 68 + d];
        Ptile[4 * wave + 0][d] = base + s0;
        Ptile[4 * wave + 1][d] = base + s1;
        Ptile[4 * wave + 2][d] = base + s2;
        Ptile[4 * wave + 3][d] = base + s3;
        __syncthreads();   // everyone done with redf before staging clobbers it
    }

    // ---- stage band rows [l0-16, l0+15] of K and V into LDS ----
    {
        const int i  = tid >> 4;            // 0..15
        const int c4 = (tid & 15) * 4;
        #pragma unroll
        for (int rnd = 0; rnd < 2; ++rnd) {
            const int ii = i + 16 * rnd;    // 0..31
            int j = l0 - 16 + ii; if (j < 0) j = 0;   // t=0 garbage rows masked later
            *(float4*)&Kband[ii][c4] = *(const float4*)(Kbh + (size_t)j * RHD + c4);
            *(float4*)&Vband[ii][c4] = *(const float4*)(Vbh + (size_t)j * RHD + c4);
        }
        __syncthreads();
    }

    for (int rr = 0; rr < 4; ++rr) {
        const int r = wave * 4 + rr;
        const int l = l0 + r;

        float4 q4 = *(const float4*)&Qbh[(size_t)l * RHD + dd * 4];
        q4.x *= SCALE; q4.y *= SCALE; q4.z *= SCALE; q4.w *= SCALE;

        float4 acc = make_float4(0.f, 0.f, 0.f, 0.f);
        float  den = 0.f;

        // ---- band from LDS: offsets 0..15 ----
        #pragma unroll
        for (int it = 0; it < 4; ++it) {
            const int off = p + 4 * it;
            const int idx = r + 16 - off;          // in [1, 31]
            const bool ok = (off <= l);
            const float4 k4 = *(const float4*)&Kband[idx][dd * 4];
            const float4 v4 = *(const float4*)&Vband[idx][dd * 4];
            float dot = q4.x * k4.x + q4.y * k4.y + q4.z * k4.z + q4.w * k4.w;
            dot = row16_sum(dot);
            float w = __expf(dot) - 1.f;
            w = ok ? w : 0.f;
            acc.x += w * v4.x; acc.y += w * v4.y;
            acc.z += w * v4.z; acc.w += w * v4.w;
            den += w;
        }
        {   // band edge offset 16 (slot p==0 only), idx = r >= 0
            const bool ok = (p == 0) && (l >= 16);
            const float4 k4 = *(const float4*)&Kband[r][dd * 4];
            const float4 v4 = *(const float4*)&Vband[r][dd * 4];
            float dot = q4.x * k4.x + q4.y * k4.y + q4.z * k4.z + q4.w * k4.w;
            dot = row16_sum(dot);
            float w = __expf(dot) - 1.f;
            w = ok ? w : 0.f;
            acc.x += w * v4.x; acc.y += w * v4.y;
            acc.z += w * v4.z; acc.w += w * v4.w;
            den += w;
        }

        // ---- combine across the 4 position groups (xor 16, 32) ----
        acc.x += __shfl_xor(acc.x, 16, 64); acc.x += __shfl_xor(acc.x, 32, 64);
        acc.y += __shfl_xor(acc.y, 16, 64); acc.y += __shfl_xor(acc.y, 32, 64);
        acc.z += __shfl_xor(acc.z, 16, 64); acc.z += __shfl_xor(acc.z, 32, 64);
        acc.w += __shfl_xor(acc.w, 16, 64); acc.w += __shfl_xor(acc.w, 32, 64);
        den   += __shfl_xor(den, 16, 64);   den   += __shfl_xor(den, 32, 64);

        if (p == 0) {
            const size_t rowix = (size_t)bh * Lc + l;
            const float4 f4 = *(const float4*)(facc + rowix * 64 + dd * 4);
            const float  fd = fden[rowix];
            acc.x += f4.x; acc.y += f4.y; acc.z += f4.z; acc.w += f4.w;
            den   += fd;
            const float inv = 1.f / ((float)(l + 1) + den);
            const float4 P4 = *(const float4*)&Ptile[r][dd * 4];
            float4 o;
            o.x = (P4.x + acc.x) * inv;
            o.y = (P4.y + acc.y) * inv;
            o.z = (P4.z + acc.z) * inv;
            o.w = (P4.w + acc.w) * inv;
            *(float4*)&out[((size_t)(b * Lc + l) * Hc + h) * Dc + dd * 4] = o;
        }
    }
}

// ---------------------------------------------------------------------------
// Fallback: original fused main kernel (band + inline far loop), used only
// when the workspace is too small for facc/fden.
// ---------------------------------------------------------------------------
__global__ __launch_bounds__(256)
void dozer_main(const float* __restrict__ Q, const float* __restrict__ K,
                const float* __restrict__ V, const float* __restrict__ partials,
                float* __restrict__ out) {
    const int bh   = blockIdx.x;
    const int t    = (NT - 1) - blockIdx.y;   // heavy tiles first
    const int b    = bh >> 3;
    const int h    = bh & 7;
    const int tid  = threadIdx.x;
    const int wave = tid >> 6;
    const int lane = tid & 63;
    const int l0   = t * TL;

    const float* Qbh = Q + (size_t)b * Lc * RHD + h * Dc;
    const float* Kbh = K + (size_t)b * Lc * RHD + h * Dc;
    const float* Vbh = V + (size_t)b * Lc * RHD + h * Dc;

    __shared__ float Kband[32][64];
    __shared__ float Vband[32][64];
    __shared__ float Ptile[TL][64];
    float (*red)[64] = (float(*)[64])Kband;

    {
        const int d = lane;
        float pbase = 0.f;
        if (partials) {
            const float* pb = partials + (size_t)bh * NT * 64;
            #pragma unroll 4
            for (int c = wave; c < t; c += 4)
                pbase += pb[(size_t)c * 64 + d];
        } else {
            for (int s = wave; s < l0; s += 4)
                pbase += Vbh[(size_t)s * RHD + d];
        }
        const float* vr = Vbh + (size_t)(l0 + 4 * wave) * RHD + d;
        const float x0 = vr[0];
        const float x1 = vr[RHD];
        const float x2 = vr[2 * RHD];
        const float x3 = vr[3 * RHD];
        const float s0 = x0, s1 = s0 + x1, s2 = s1 + x2, s3 = s2 + x3;
        red[wave][d]     = pbase;
        red[4 + wave][d] = s3;
        __syncthreads();
        float base = red[0][d] + red[1][d] + red[2][d] + red[3][d];
        if (wave > 0) base += red[4][d];
        if (wave > 1) base += red[5][d];
        if (wave > 2) base += red[6][d];
        Ptile[4 * wave + 0][d] = base + s0;
        Ptile[4 * wave + 1][d] = base + s1;
        Ptile[4 * wave + 2][d] = base + s2;
        Ptile[4 * wave + 3][d] = base + s3;
        __syncthreads();
    }

    {
        const int i  = tid >> 4;
        const int c4 = (tid & 15) * 4;
        #pragma unroll
        for (int rnd = 0; rnd < 2; ++rnd) {
            const int ii = i + 16 * rnd;
            int j = l0 - 16 + ii; if (j < 0) j = 0;
            *(float4*)&Kband[ii][c4] = *(const float4*)(Kbh + (size_t)j * RHD + c4);
            *(float4*)&Vband[ii][c4] = *(const float4*)(Vbh + (size_t)j * RHD + c4);
        }
        __syncthreads();
    }

    const int p  = lane >> 4;
    const int dd = lane & 15;

    for (int rr = 0; rr < 4; ++rr) {
        const int r = wave * 4 + rr;
        const int l = l0 + r;
        const int nk   = l / SP1;
        const int nfar = (nk + 3) >> 2;

        float4 q4 = *(const float4*)&Qbh[(size_t)l * RHD + dd * 4];
        q4.x *= SCALE; q4.y *= SCALE; q4.z *= SCALE; q4.w *= SCALE;

        float4 acc = make_float4(0.f, 0.f, 0.f, 0.f);
        float  den = 0.f;

        auto farload = [&](float4& k4, float4& v4, int m) {
            const int f = 1 + p + 4 * m;
            int j = l - SP1 * f; if (j < 0) j = 0;
            k4 = *(const float4*)(Kbh + (size_t)j * RHD + dd * 4);
            v4 = *(const float4*)(Vbh + (size_t)j * RHD + dd * 4);
        };
        auto farstep = [&](const float4& k4, const float4& v4, int m) {
            const int f = 1 + p + 4 * m;
            const bool ok = (f <= nk);
            float dot = q4.x * k4.x + q4.y * k4.y + q4.z * k4.z + q4.w * k4.w;
            dot = row16_sum(dot);
            float w = __expf(dot) - 1.f;
            w = ok ? w : 0.f;
            acc.x += w * v4.x; acc.y += w * v4.y;
            acc.z += w * v4.z; acc.w += w * v4.w;
            den += w;
        };

        float4 kA = make_float4(0.f,0.f,0.f,0.f), vA = kA, kB = kA, vB = kA;
        if (nfar > 0) farload(kA, vA, 0);
        if (nfar > 1) farload(kB, vB, 1);

        #pragma unroll
        for (int it = 0; it < 4; ++it) {
            const int off = p + 4 * it;
            const int idx = r + 16 - off;
            const bool ok = (off <= l);
            const float4 k4 = *(const float4*)&Kband[idx][dd * 4];
            const float4 v4 = *(const float4*)&Vband[idx][dd * 4];
            float dot = q4.x * k4.x + q4.y * k4.y + q4.z * k4.z + q4.w * k4.w;
            dot = row16_sum(dot);
            float w = __expf(dot) - 1.f;
            w = ok ? w : 0.f;
            acc.x += w * v4.x; acc.y += w * v4.y;
            acc.z += w * v4.z; acc.w += w * v4.w;
            den += w;
        }
        {
            const bool ok = (p == 0) && (l >= 16);
            const float4 k4 = *(const float4*)&Kband[r][dd * 4];
            const float4 v4 = *(const float4*)&Vband[r][dd * 4];
            float dot = q4.x * k4.x + q4.y * k4.y + q4.z * k4.z + q4.w * k4.w;
            dot = row16_sum(dot);
            float w = __expf(dot) - 1.f;
            w = ok ? w : 0.f;
            acc.x += w * v4.x; acc.y += w * v4.y;
            acc.z += w * v4.z; acc.w += w * v4.w;
            den += w;
        }

        int m = 0;
        for (; m + 1 < nfar; m += 2) {
            farstep(kA, vA, m);
            if (m + 2 < nfar) farload(kA, vA, m + 2);
            farstep(kB, vB, m + 1);
            if (m + 3 < nfar) farload(kB, vB, m + 3);
        }
        if (m < nfar) farstep(kA, vA, m);

        acc.x += __shfl_xor(acc.x, 16, 64); acc.x += __shfl_xor(acc.x, 32, 64);
        acc.y += __shfl_xor(acc.y, 16, 64); acc.y += __shfl_xor(acc.y, 32, 64);
        acc.z += __shfl_xor(acc.z, 16, 64); acc.z += __shfl_xor(acc.z, 32, 64);
        acc.w += __shfl_xor(acc.w, 16, 64); acc.w += __shfl_xor(acc.w, 32, 64);
        den   += __shfl_xor(den, 16, 64);   den   += __shfl_xor(den, 32, 64);

        const float inv = 1.f / ((float)(l + 1) + den);
        if (p == 0) {
            const float4 P4 = *(const float4*)&Ptile[r][dd * 4];
            float4 o;
            o.x = (P4.x + acc.x) * inv;
            o.y = (P4.y + acc.y) * inv;
            o.z = (P4.z + acc.z) * inv;
            o.w = (P4.w + acc.w) * inv;
            *(float4*)&out[((size_t)(b * Lc + l) * Hc + h) * Dc + dd * 4] = o;
        }
    }
}

// ---------------------------------------------------------------------------
extern "C" void kernel_launch(void* const* d_in, const int* in_sizes, int n_in,
                              void* d_out, int out_size, void* d_ws, size_t ws_size,
                              hipStream_t stream) {
    // inputs: 0=x (unused), 1=queries, 2=keys, 3=values, 4=attn_mask (analytic)
    const float* Q = (const float*)d_in[1];
    const float* K = (const float*)d_in[2];
    const float* V = (const float*)d_in[3];
    float* out = (float*)d_out;

    const size_t np = (size_t)Bc * Hc * NT * 64 * sizeof(float);   // 512 KB
    const size_t nf = (size_t)Bc * Hc * Lc * 64 * sizeof(float);   // 8.39 MB
    const size_t nd = (size_t)Bc * Hc * Lc * sizeof(float);        // 128 KB

    dim3 grid(Bc * Hc, NT);   // bh fastest: balances per-CU tile mix
    if (ws_size >= np + nf + nd && d_ws != nullptr) {
        char* ws = (char*)d_ws;
        float* partials = (float*)ws;
        float* facc     = (float*)(ws + np);
        float* fden     = (float*)(ws + np + nf);
        dozer_chunk_sum<<<grid, 256, 0, stream>>>(V, partials);
        dozer_far<<<dim3(Bc * Hc, SP1), 256, 0, stream>>>(Q, K, V, facc, fden);
        dozer_main_lite<<<grid, 256, 0, stream>>>(Q, K, V, partials, facc, fden, out);
    } else {
        float* partials = (ws_size >= np && d_ws != nullptr) ? (float*)d_ws : nullptr;
        if (partials)
            dozer_chunk_sum<<<grid, 256, 0, stream>>>(V, partials);
        dozer_main<<<grid, 256, 0, stream>>>(Q, K, V, partials, out);
    }
}

// Round 3
// 121.778 us; speedup vs baseline: 1.0225x; 1.0225x over previous
//
#include <hip/hip_runtime.h>

// Problem constants: B=2, L=2048, H=8, D=64, window=32, stride=64
#define Bc 2
#define Lc 2048
#define Hc 8
#define Dc 64
#define TL 16                 // rows per block
#define NT (Lc / TL)          // 128 tiles
#define RHD (Hc * Dc)         // 512 floats between consecutive s rows
#define SP1 65                // stride+1
#define SCALE 0.125f          // 1/sqrt(64)

// DPP-based add of a permuted copy: pure VALU, no DS traffic.
template <int CTRL>
__device__ __forceinline__ float dpp_add(float x) {
    int p = __builtin_amdgcn_update_dpp(0, __float_as_int(x), CTRL, 0xF, 0xF, true);
    return x + __int_as_float(p);
}
// 16-lane-row sum (verified R3/R4): xor1, xor2, half-mirror, mirror.
__device__ __forceinline__ float row16_sum(float x) {
    x = dpp_add<0xB1>(x);
    x = dpp_add<0x4E>(x);
    x = dpp_add<0x141>(x);
    x = dpp_add<0x140>(x);
    return x;
}

// ---------------------------------------------------------------------------
// Kernel 1: per-(b,h) tile sums of V -> partials[bh][t][d]
// ---------------------------------------------------------------------------
__global__ __launch_bounds__(256)
void dozer_chunk_sum(const float* __restrict__ V, float* __restrict__ partials) {
    const int bh = blockIdx.x;
    const int t  = blockIdx.y;
    const int b  = bh >> 3;
    const int h  = bh & 7;
    const int g  = threadIdx.x >> 6;
    const int d  = threadIdx.x & 63;
    const float* Vbh = V + (size_t)b * Lc * RHD + h * Dc;
    const int l0 = t * TL;
    float s = 0.f;
    for (int r = g; r < TL; r += 4)
        s += Vbh[(size_t)(l0 + r) * RHD + d];
    __shared__ float red[4][64];
    red[g][d] = s;
    __syncthreads();
    if (g == 0)
        partials[((size_t)bh * NT + t) * 64 + d] =
            red[0][d] + red[1][d] + red[2][d] + red[3][d];
}

// ---------------------------------------------------------------------------
// Kernel 2: fused main kernel. Block = (bh, tile of 16 rows), 4 waves,
// 4 rows/wave. Lane layout: p = lane>>4 (slot 0..3), dd = lane&15 (d-quad).
//
// Latency plan (this revision):
//  - Band K/V staged global->REG at kernel start (T14); ds_write AFTER the
//    prefix phase consumes the aliased LDS scratch. Prefix covers the load
//    latency; staging is no longer an exposed window.
//  - Prefix partials read as float4 in <=2 predicated batches of 4
//    (2 latency windows max instead of 8 serialized scalar groups).
//  - Far loop: depth-4 rotating prefetch; the 4 prologue load-pairs are
//    issued BEFORE the band phase, so band compute (~275 cyc) covers them.
//    Rows with nfar<=4 (half of all rows) have a fully-covered far phase.
//    Steady state: farload(m+4) issued after farstep(m) -> ~3 farsteps
//    (~165 cyc) of cover vs ~55 at depth-2.
// LDS: Kband 8K + Vband 8K + Ptile 4K = 20480 B. __launch_bounds__(256,4)
// keeps the VGPR class <=128 (4 waves/SIMD).
// ---------------------------------------------------------------------------
__global__ __launch_bounds__(256, 4)
void dozer_main(const float* __restrict__ Q, const float* __restrict__ K,
                const float* __restrict__ V, const float* __restrict__ partials,
                float* __restrict__ out) {
    const int bh   = blockIdx.x;
    const int t    = (NT - 1) - blockIdx.y;   // heavy tiles first
    const int b    = bh >> 3;
    const int h    = bh & 7;
    const int tid  = threadIdx.x;
    const int wave = tid >> 6;
    const int lane = tid & 63;
    const int l0   = t * TL;
    const int p    = lane >> 4;
    const int dd   = lane & 15;

    const float* Qbh = Q + (size_t)b * Lc * RHD + h * Dc;
    const float* Kbh = K + (size_t)b * Lc * RHD + h * Dc;
    const float* Vbh = V + (size_t)b * Lc * RHD + h * Dc;

    __shared__ float Kband[32][64];
    __shared__ float Vband[32][64];
    __shared__ float Ptile[TL][64];
    // redf aliases Kband rows 0..19 (5120 B < 8192 B): prefix scratch, fully
    // consumed before the band ds_writes clobber it.
    float* redf = &Kband[0][0];

    // ---- 1. issue band staging loads into registers (write to LDS later) ----
    const int si = tid >> 4;            // 0..15
    const int c4 = (tid & 15) * 4;
    int jb0 = l0 - 16 + si; if (jb0 < 0) jb0 = 0;   // t=0 garbage masked later
    const int jb1 = l0 + si;                        // always >= 0
    const float4 kS0 = *(const float4*)(Kbh + (size_t)jb0 * RHD + c4);
    const float4 vS0 = *(const float4*)(Vbh + (size_t)jb0 * RHD + c4);
    const float4 kS1 = *(const float4*)(Kbh + (size_t)jb1 * RHD + c4);
    const float4 vS1 = *(const float4*)(Vbh + (size_t)jb1 * RHD + c4);

    // ---- 2. prefix phase (covers band-load latency) ----
    {
        const int cc0 = 4 * wave + p;   // slot id 0..15
        float4 pa = make_float4(0.f, 0.f, 0.f, 0.f);
        if (partials) {
            const float* pb = partials + (size_t)bh * NT * 64 + dd * 4;
            if (t > 0) {    // batch 1: tiles cc0+{0,16,32,48}
                const float4 f0 = *(const float4*)(pb + (size_t)(cc0     ) * 64);
                const float4 f1 = *(const float4*)(pb + (size_t)(cc0 + 16) * 64);
                const float4 f2 = *(const float4*)(pb + (size_t)(cc0 + 32) * 64);
                const float4 f3 = *(const float4*)(pb + (size_t)(cc0 + 48) * 64);
                if (cc0      < t) { pa.x += f0.x; pa.y += f0.y; pa.z += f0.z; pa.w += f0.w; }
                if (cc0 + 16 < t) { pa.x += f1.x; pa.y += f1.y; pa.z += f1.z; pa.w += f1.w; }
                if (cc0 + 32 < t) { pa.x += f2.x; pa.y += f2.y; pa.z += f2.z; pa.w += f2.w; }
                if (cc0 + 48 < t) { pa.x += f3.x; pa.y += f3.y; pa.z += f3.z; pa.w += f3.w; }
            }
            if (t > 64) {   // batch 2: tiles cc0+{64,80,96,112}
                const float4 f4 = *(const float4*)(pb + (size_t)(cc0 +  64) * 64);
                const float4 f5 = *(const float4*)(pb + (size_t)(cc0 +  80) * 64);
                const float4 f6 = *(const float4*)(pb + (size_t)(cc0 +  96) * 64);
                const float4 f7 = *(const float4*)(pb + (size_t)(cc0 + 112) * 64);
                if (cc0 +  64 < t) { pa.x += f4.x; pa.y += f4.y; pa.z += f4.z; pa.w += f4.w; }
                if (cc0 +  80 < t) { pa.x += f5.x; pa.y += f5.y; pa.z += f5.z; pa.w += f5.w; }
                if (cc0 +  96 < t) { pa.x += f6.x; pa.y += f6.y; pa.z += f6.z; pa.w += f6.w; }
                if (cc0 + 112 < t) { pa.x += f7.x; pa.y += f7.y; pa.z += f7.z; pa.w += f7.w; }
            }
        } else {
            // no-workspace fallback: sum V rows directly, slot-strided, float4
            for (int s = cc0; s < l0; s += 16) {
                const float4 v4 = *(const float4*)(Vbh + (size_t)s * RHD + dd * 4);
                pa.x += v4.x; pa.y += v4.y; pa.z += v4.z; pa.w += v4.w;
            }
        }
        *(float4*)&redf[cc0 * 64 + dd * 4] = pa;

        // V carry rows (scalar-d layout)
        const int d = lane;
        const float* vr = Vbh + (size_t)(l0 + 4 * wave) * RHD + d;
        const float x0 = vr[0];
        const float x1 = vr[RHD];
        const float x2 = vr[2 * RHD];
        const float x3 = vr[3 * RHD];
        const float s0 = x0, s1 = s0 + x1, s2 = s1 + x2, s3 = s2 + x3;
        redf[(16 + wave) * 64 + d] = s3;
        __syncthreads();
        float base = 0.f;
        #pragma unroll
        for (int r2 = 0; r2 < 16; ++r2) base += redf[r2 * 64 + d];
        if (wave > 0) base += redf[16 * 64 + d];
        if (wave > 1) base += redf[17 * 64 + d];
        if (wave > 2) base += redf[18 * 64 + d];
        Ptile[4 * wave + 0][d] = base + s0;
        Ptile[4 * wave + 1][d] = base + s1;
        Ptile[4 * wave + 2][d] = base + s2;
        Ptile[4 * wave + 3][d] = base + s3;
        __syncthreads();   // everyone done with redf before staging clobbers it
    }

    // ---- 3. write staged band rows to LDS ----
    *(float4*)&Kband[si][c4]      = kS0;
    *(float4*)&Vband[si][c4]      = vS0;
    *(float4*)&Kband[si + 16][c4] = kS1;
    *(float4*)&Vband[si + 16][c4] = vS1;
    __syncthreads();

    for (int rr = 0; rr < 4; ++rr) {
        const int r = wave * 4 + rr;
        const int l = l0 + r;
        const int nk   = l / SP1;            // far offsets 65f, f = 1..nk
        const int nfar = (nk + 3) >> 2;      // far iterations (4 slots each)

        float4 q4 = *(const float4*)&Qbh[(size_t)l * RHD + dd * 4];
        q4.x *= SCALE; q4.y *= SCALE; q4.z *= SCALE; q4.w *= SCALE;

        float4 acc = make_float4(0.f, 0.f, 0.f, 0.f);
        float  den = 0.f;

        auto farload = [&](float4& k4, float4& v4, int m) {
            const int f = 1 + p + 4 * m;
            int j = l - SP1 * f; if (j < 0) j = 0;
            k4 = *(const float4*)(Kbh + (size_t)j * RHD + dd * 4);
            v4 = *(const float4*)(Vbh + (size_t)j * RHD + dd * 4);
        };
        auto farstep = [&](const float4& k4, const float4& v4, int m) {
            const int f = 1 + p + 4 * m;
            const bool ok = (f <= nk);
            float dot = q4.x * k4.x + q4.y * k4.y + q4.z * k4.z + q4.w * k4.w;
            dot = row16_sum(dot);
            float w = __expf(dot) - 1.f;
            w = ok ? w : 0.f;
            acc.x += w * v4.x; acc.y += w * v4.y;
            acc.z += w * v4.z; acc.w += w * v4.w;
            den += w;
        };

        // far prologue: issue up to 4 load-pairs NOW; band phase covers them
        float4 k0, v0, k1, v1, k2, v2, k3, v3;
        if (nfar > 0) farload(k0, v0, 0);
        if (nfar > 1) farload(k1, v1, 1);
        if (nfar > 2) farload(k2, v2, 2);
        if (nfar > 3) farload(k3, v3, 3);

        // ---- band from LDS: offsets 0..15 ----
        #pragma unroll
        for (int it = 0; it < 4; ++it) {
            const int off = p + 4 * it;
            const int idx = r + 16 - off;          // in [1, 31]
            const bool ok = (off <= l);
            const float4 k4 = *(const float4*)&Kband[idx][dd * 4];
            const float4 v4 = *(const float4*)&Vband[idx][dd * 4];
            float dot = q4.x * k4.x + q4.y * k4.y + q4.z * k4.z + q4.w * k4.w;
            dot = row16_sum(dot);
            float w = __expf(dot) - 1.f;
            w = ok ? w : 0.f;
            acc.x += w * v4.x; acc.y += w * v4.y;
            acc.z += w * v4.z; acc.w += w * v4.w;
            den += w;
        }
        {   // band edge offset 16 (slot p==0 only), idx = r >= 0
            const bool ok = (p == 0) && (l >= 16);
            const float4 k4 = *(const float4*)&Kband[r][dd * 4];
            const float4 v4 = *(const float4*)&Vband[r][dd * 4];
            float dot = q4.x * k4.x + q4.y * k4.y + q4.z * k4.z + q4.w * k4.w;
            dot = row16_sum(dot);
            float w = __expf(dot) - 1.f;
            w = ok ? w : 0.f;
            acc.x += w * v4.x; acc.y += w * v4.y;
            acc.z += w * v4.z; acc.w += w * v4.w;
            den += w;
        }

        // ---- far loop: depth-4 rotating prefetch, unrolled by 4 ----
        int m = 0;
        for (; m + 4 <= nfar; m += 4) {
            farstep(k0, v0, m    ); if (m + 4 < nfar) farload(k0, v0, m + 4);
            farstep(k1, v1, m + 1); if (m + 5 < nfar) farload(k1, v1, m + 5);
            farstep(k2, v2, m + 2); if (m + 6 < nfar) farload(k2, v2, m + 6);
            farstep(k3, v3, m + 3); if (m + 7 < nfar) farload(k3, v3, m + 7);
        }
        if (m     < nfar) farstep(k0, v0, m);
        if (m + 1 < nfar) farstep(k1, v1, m + 1);
        if (m + 2 < nfar) farstep(k2, v2, m + 2);
        // (m+3 < nfar impossible: loop exits with nfar - m <= 3)

        // ---- combine across the 4 position groups (xor 16, 32) ----
        acc.x += __shfl_xor(acc.x, 16, 64); acc.x += __shfl_xor(acc.x, 32, 64);
        acc.y += __shfl_xor(acc.y, 16, 64); acc.y += __shfl_xor(acc.y, 32, 64);
        acc.z += __shfl_xor(acc.z, 16, 64); acc.z += __shfl_xor(acc.z, 32, 64);
        acc.w += __shfl_xor(acc.w, 16, 64); acc.w += __shfl_xor(acc.w, 32, 64);
        den   += __shfl_xor(den, 16, 64);   den   += __shfl_xor(den, 32, 64);

        const float inv = 1.f / ((float)(l + 1) + den);
        if (p == 0) {
            const float4 P4 = *(const float4*)&Ptile[r][dd * 4];
            float4 o;
            o.x = (P4.x + acc.x) * inv;
            o.y = (P4.y + acc.y) * inv;
            o.z = (P4.z + acc.z) * inv;
            o.w = (P4.w + acc.w) * inv;
            *(float4*)&out[((size_t)(b * Lc + l) * Hc + h) * Dc + dd * 4] = o;
        }
    }
}

// ---------------------------------------------------------------------------
extern "C" void kernel_launch(void* const* d_in, const int* in_sizes, int n_in,
                              void* d_out, int out_size, void* d_ws, size_t ws_size,
                              hipStream_t stream) {
    // inputs: 0=x (unused), 1=queries, 2=keys, 3=values, 4=attn_mask (analytic)
    const float* Q = (const float*)d_in[1];
    const float* K = (const float*)d_in[2];
    const float* V = (const float*)d_in[3];
    float* out = (float*)d_out;

    const size_t np = (size_t)Bc * Hc * NT * 64 * sizeof(float);  // 512 KB
    float* partials = (ws_size >= np && d_ws != nullptr) ? (float*)d_ws : nullptr;

    dim3 grid(Bc * Hc, NT);   // bh fastest: balances per-CU tile mix
    if (partials)
        dozer_chunk_sum<<<grid, 256, 0, stream>>>(V, partials);
    dozer_main<<<grid, 256, 0, stream>>>(Q, K, V, partials, out);
}